// Round 7
// baseline (59.226 us; speedup 1.0000x reference)
//
#include <hip/hip_runtime.h>

#define NC 1024
#define NS 32
#define DD 512
#define MARGIN 0.3f
#define FXSCALE 1048576.0  // 2^20 fixed-point for the deterministic integer mean

// One block per class, 512 threads, thread t owns scalar column t.
// All 32 pos + 32 neg rows of that column are loaded into registers (64
// independent coalesced dword loads -> max MLP, each HBM byte read once).
// Anchor is thread-local (mean over the thread's own 32 pos values): no LDS
// round-trip, no barrier until the final cross-wave combine.
//
// Codegen rule #20: every array index is compile-time static (literal loop
// bounds only) so p[]/n[] stay in VGPRs. R3-R5 lesson: a fused tail with a
// __syncthreads() inside divergent control flow demotes the arrays to
// scratch (VGPR 40/72, ~100us). This tail is barrier-free: one thread does
// a fixed-point u64 atomicAdd (associative -> bit-deterministic) + a done
// counter; the last block converts and stores the mean.
__global__ __launch_bounds__(512) void ccl_fused(const float* __restrict__ emb,
                                                 unsigned long long* __restrict__ acc,
                                                 unsigned* __restrict__ cnt,
                                                 float* __restrict__ out) {
    const int c = blockIdx.x;
    const int t = threadIdx.x;
    const int lane = t & 63;
    const int wv = t >> 6;
    const float* pos = emb + (size_t)c * (2 * NS * DD);
    const float* neg = pos + NS * DD;

    __shared__ float s_wap[8][32];
    __shared__ float s_wnd[8][32];

    // ---- load entire column: 32 pos then 32 neg (all issued up front) ----
    float p[32], n[32];
#pragma unroll
    for (int s = 0; s < 32; ++s) p[s] = pos[s * DD + t];
#pragma unroll
    for (int s = 0; s < 32; ++s) n[s] = neg[s * DD + t];

    // ---- thread-local anchor for this column ----
    float a = 0.f;
#pragma unroll
    for (int s = 0; s < 32; ++s) a += p[s];
    a *= (1.f / NS);

    // ---- square diffs in place ----
#pragma unroll
    for (int s = 0; s < 32; ++s) { float d = p[s] - a; p[s] = d * d; }
#pragma unroll
    for (int s = 0; s < 32; ++s) { float d = n[s] - a; n[s] = d * d; }

    // ---- halving butterfly across the wave's 64 columns ----
    // Step mask m pairs lanes l, l^m; the (l&m)-set lane keeps the hi half.
#define BSTEP(arr, m, half)                                        \
    {                                                              \
        _Pragma("unroll")                                          \
        for (int i = 0; i < (half); ++i) {                         \
            float lo = arr[i], hi = arr[i + (half)];               \
            float send = (lane & (m)) ? lo : hi;                   \
            float recv = __shfl_xor(send, (m));                    \
            arr[i] = (lane & (m)) ? (hi + recv) : (lo + recv);     \
        }                                                          \
    }
    BSTEP(p, 1, 16) BSTEP(p, 2, 8) BSTEP(p, 4, 4) BSTEP(p, 8, 2) BSTEP(p, 16, 1)
    BSTEP(n, 1, 16) BSTEP(n, 2, 8) BSTEP(n, 4, 4) BSTEP(n, 8, 2) BSTEP(n, 16, 1)
#undef BSTEP
    // lane l holds element j = bitrev5(l&31) summed over its 32-lane half;
    // fold the two halves of the wave:
    float rap = p[0] + __shfl_xor(p[0], 32);
    float rnd = n[0] + __shfl_xor(n[0], 32);
    if (lane < 32) {
        const int jm = ((lane & 1) << 4) | ((lane & 2) << 2) | (lane & 4) |
                       ((lane & 8) >> 2) | ((lane & 16) >> 4);
        s_wap[wv][jm] = rap;
        s_wnd[wv][jm] = rnd;
    }
    __syncthreads();

    // ---- combine 8 waves; min + hinge in lanes 0-31 of wave 0 ----
    if (t < NS) {
        float ap = 0.f, nd = 0.f;
#pragma unroll
        for (int w = 0; w < 8; ++w) { ap += s_wap[w][t]; nd += s_wnd[w][t]; }
        float an = nd;
#pragma unroll
        for (int m = 1; m < 32; m <<= 1) an = fminf(an, __shfl_xor(an, m));
        float l = fmaxf(ap - an + MARGIN, 0.f);
#pragma unroll
        for (int m = 1; m < 32; m <<= 1) l += __shfl_xor(l, m);
        if (t == 0) {
            // deterministic fused mean: integer fixed-point accumulate
            unsigned long long fx =
                (unsigned long long)(long long)((double)l * FXSCALE + 0.5);
            __hip_atomic_fetch_add(acc, fx, __ATOMIC_RELAXED, __HIP_MEMORY_SCOPE_AGENT);
            unsigned old = __hip_atomic_fetch_add(cnt, 1u, __ATOMIC_ACQ_REL,
                                                  __HIP_MEMORY_SCOPE_AGENT);
            if (old == NC - 1) {
                unsigned long long tot =
                    __hip_atomic_load(acc, __ATOMIC_ACQUIRE, __HIP_MEMORY_SCOPE_AGENT);
                out[0] = (float)((double)tot * (1.0 / (FXSCALE * NC)));
            }
        }
    }
}

extern "C" void kernel_launch(void* const* d_in, const int* in_sizes, int n_in,
                              void* d_out, int out_size, void* d_ws, size_t ws_size,
                              hipStream_t stream) {
    const float* emb = (const float*)d_in[0];            // (2*NC*NS, DD) f32
    unsigned* cnt = (unsigned*)d_ws;                     // done counter (offset 0)
    unsigned long long* acc = (unsigned long long*)((char*)d_ws + 8);  // fx accumulator
    float* out = (float*)d_out;                          // 1 float
    hipMemsetAsync(d_ws, 0, 16, stream);                 // zero cnt + acc each call
    ccl_fused<<<NC, 512, 0, stream>>>(emb, acc, cnt, out);
}

// Round 8
// 46.238 us; speedup vs baseline: 1.2809x; 1.2809x over previous
//
#include <hip/hip_runtime.h>

#define NC 1024
#define NS 32
#define DD 512
#define MARGIN 0.3f
#define FXSCALE 1048576.0  // 2^20 fixed-point: deterministic integer mean

// One block per class, 512 threads, thread t owns scalar column t.
// All 32 pos + 32 neg rows of that column are loaded into registers (64
// independent coalesced dword loads -> max MLP, each HBM byte read once).
// Anchor is thread-local. Body is byte-identical to the proven R6 kernel
// (29.4 us total, no scratch demotion).
//
// Fused mean tail (replaces the 2nd kernel): plain atomicAdd builtins only.
// R3-R5/R7 lesson: __hip_atomic_* intrinsics (explicit memory orders ->
// fences) demote p[]/n[] to scratch (VGPR 40-72, ~95us). Ordering here is
// ISA-level instead: the acc atomicAdd's RESULT is kept live (asm sink), so
// the compiler emits the returning opcode + s_waitcnt before the cnt add
// issues -> every counted block's contribution is already at the coherent
// point. The last block re-reads acc with atomicAdd(acc,0) (an RMW, served
// at the coherent point -- no stale cache, no fence).
__global__ __launch_bounds__(512) void ccl_fused(const float* __restrict__ emb,
                                                 unsigned long long* __restrict__ acc,
                                                 unsigned* __restrict__ cnt,
                                                 float* __restrict__ out) {
    const int c = blockIdx.x;
    const int t = threadIdx.x;
    const int lane = t & 63;
    const int wv = t >> 6;
    const float* pos = emb + (size_t)c * (2 * NS * DD);
    const float* neg = pos + NS * DD;

    __shared__ float s_wap[8][32];
    __shared__ float s_wnd[8][32];

    // ---- load entire column: 32 pos then 32 neg (all issued up front) ----
    float p[32], n[32];
#pragma unroll
    for (int s = 0; s < 32; ++s) p[s] = pos[s * DD + t];
#pragma unroll
    for (int s = 0; s < 32; ++s) n[s] = neg[s * DD + t];

    // ---- thread-local anchor for this column ----
    float a = 0.f;
#pragma unroll
    for (int s = 0; s < 32; ++s) a += p[s];
    a *= (1.f / NS);

    // ---- square diffs in place ----
#pragma unroll
    for (int s = 0; s < 32; ++s) { float d = p[s] - a; p[s] = d * d; }
#pragma unroll
    for (int s = 0; s < 32; ++s) { float d = n[s] - a; n[s] = d * d; }

    // ---- halving butterfly across the wave's 64 columns ----
    // Step mask m pairs lanes l, l^m; the (l&m)-set lane keeps the hi half.
#define BSTEP(arr, m, half)                                        \
    {                                                              \
        _Pragma("unroll")                                          \
        for (int i = 0; i < (half); ++i) {                         \
            float lo = arr[i], hi = arr[i + (half)];               \
            float send = (lane & (m)) ? lo : hi;                   \
            float recv = __shfl_xor(send, (m));                    \
            arr[i] = (lane & (m)) ? (hi + recv) : (lo + recv);     \
        }                                                          \
    }
    BSTEP(p, 1, 16) BSTEP(p, 2, 8) BSTEP(p, 4, 4) BSTEP(p, 8, 2) BSTEP(p, 16, 1)
    BSTEP(n, 1, 16) BSTEP(n, 2, 8) BSTEP(n, 4, 4) BSTEP(n, 8, 2) BSTEP(n, 16, 1)
#undef BSTEP
    // lane l holds element j = bitrev5(l&31) summed over its 32-lane half;
    // fold the two halves of the wave:
    float rap = p[0] + __shfl_xor(p[0], 32);
    float rnd = n[0] + __shfl_xor(n[0], 32);
    if (lane < 32) {
        const int jm = ((lane & 1) << 4) | ((lane & 2) << 2) | (lane & 4) |
                       ((lane & 8) >> 2) | ((lane & 16) >> 4);
        s_wap[wv][jm] = rap;
        s_wnd[wv][jm] = rnd;
    }
    __syncthreads();

    // ---- combine 8 waves; min + hinge in lanes 0-31 of wave 0 ----
    if (t < NS) {
        float ap = 0.f, nd = 0.f;
#pragma unroll
        for (int w = 0; w < 8; ++w) { ap += s_wap[w][t]; nd += s_wnd[w][t]; }
        float an = nd;
#pragma unroll
        for (int m = 1; m < 32; m <<= 1) an = fminf(an, __shfl_xor(an, m));
        float l = fmaxf(ap - an + MARGIN, 0.f);
#pragma unroll
        for (int m = 1; m < 32; m <<= 1) l += __shfl_xor(l, m);
        if (t == 0) {
            unsigned long long fx =
                (unsigned long long)(long long)((double)l * FXSCALE + 0.5);
            // Returning atomic add; keep result live so the waitcnt orders it
            // before the counter bump (ISA-level release).
            unsigned long long prev = atomicAdd(acc, fx);
            asm volatile("" :: "v"(prev));
            unsigned old = atomicAdd(cnt, 1u);
            if (old == NC - 1) {
                // RMW read-back: served at the coherent point, sees all adds.
                unsigned long long tot = atomicAdd(acc, 0ull);
                out[0] = (float)((double)tot * (1.0 / (FXSCALE * NC)));
            }
        }
    }
}

extern "C" void kernel_launch(void* const* d_in, const int* in_sizes, int n_in,
                              void* d_out, int out_size, void* d_ws, size_t ws_size,
                              hipStream_t stream) {
    const float* emb = (const float*)d_in[0];            // (2*NC*NS, DD) f32
    unsigned* cnt = (unsigned*)d_ws;                     // done counter (offset 0)
    unsigned long long* acc = (unsigned long long*)((char*)d_ws + 8);  // fx accumulator
    float* out = (float*)d_out;                          // 1 float
    hipMemsetAsync(d_ws, 0, 16, stream);                 // zero cnt + acc each call
    ccl_fused<<<NC, 512, 0, stream>>>(emb, acc, cnt, out);
}

// Round 9
// 31.986 us; speedup vs baseline: 1.8516x; 1.4456x over previous
//
#include <hip/hip_runtime.h>

#define NC 1024
#define NS 32
#define DD 512
#define MARGIN 0.3f

// Kernel 1: one block per class, 1024 threads. Thread t = (g, col):
// g = t>>9 picks sample parity (rows s = 2j+g, j<16), col = t&511 its scalar
// column. Per-thread data drops to 16 pos + 16 neg regs (vs 64 in the R6
// shape) -> target VGPR <= 64 -> 32 waves/CU, 2x the resident waves during
// the load phase. Anchor needs a cross-parity combine: 4 KB LDS + 1 barrier.
//
// Codegen rules (hard-won R3-R8): literal loop bounds only (SROA), NO
// atomics / __hip_atomic_* anywhere in this kernel (they demote the arrays
// to scratch or serialize at the coherent point), separate reduce kernel.
__global__ __launch_bounds__(1024) void ccl_per_class(const float* __restrict__ emb,
                                                      float* __restrict__ cls) {
    const int c = blockIdx.x;
    const int t = threadIdx.x;
    const int g = t >> 9;
    const int col = t & 511;
    const int lane = t & 63;
    const int wv = t >> 6;
    const float* pos = emb + (size_t)c * (2 * NS * DD);
    const float* neg = pos + NS * DD;

    __shared__ float s_part[2][DD];   // per-parity column sums (anchor)
    __shared__ float s_wap[16][16];   // per-wave sample partials (ap)
    __shared__ float s_wnd[16][16];   // per-wave sample partials (nd)

    // ---- load 16 pos + 16 neg rows of this column (rows s = 2j+g) ----
    float p[16], n[16];
#pragma unroll
    for (int j = 0; j < 16; ++j) p[j] = pos[(2 * j + g) * DD + col];
#pragma unroll
    for (int j = 0; j < 16; ++j) n[j] = neg[(2 * j + g) * DD + col];

    // ---- anchor: half-column sum, LDS combine across the two parities ----
    float a = p[0];
#pragma unroll
    for (int j = 1; j < 16; ++j) a += p[j];
    s_part[g][col] = a;
    __syncthreads();
    a = (s_part[0][col] + s_part[1][col]) * (1.f / NS);

    // ---- square diffs in place ----
#pragma unroll
    for (int j = 0; j < 16; ++j) { float d = p[j] - a; p[j] = d * d; }
#pragma unroll
    for (int j = 0; j < 16; ++j) { float d = n[j] - a; n[j] = d * d; }

    // ---- halving butterfly across the wave's 64 columns ----
    // Step mask m pairs lanes l, l^m; the (l&m)-set lane keeps the hi half.
#define BSTEP(arr, m, half)                                        \
    {                                                              \
        _Pragma("unroll")                                          \
        for (int i = 0; i < (half); ++i) {                         \
            float lo = arr[i], hi = arr[i + (half)];               \
            float send = (lane & (m)) ? lo : hi;                   \
            float recv = __shfl_xor(send, (m));                    \
            arr[i] = (lane & (m)) ? (hi + recv) : (lo + recv);     \
        }                                                          \
    }
    BSTEP(p, 1, 8) BSTEP(p, 2, 4) BSTEP(p, 4, 2) BSTEP(p, 8, 1)
    BSTEP(n, 1, 8) BSTEP(n, 2, 4) BSTEP(n, 4, 2) BSTEP(n, 8, 1)
#undef BSTEP
    // lane holds element j = bitrev4(lane&15) summed over its 16-lane group;
    // fold the four groups of the wave:
    float rap = p[0];
    rap += __shfl_xor(rap, 16);
    rap += __shfl_xor(rap, 32);
    float rnd = n[0];
    rnd += __shfl_xor(rnd, 16);
    rnd += __shfl_xor(rnd, 32);
    if (lane < 16) {
        const int jm = ((lane & 1) << 3) | ((lane & 2) << 1) | ((lane & 4) >> 1) | ((lane & 8) >> 3);
        s_wap[wv][jm] = rap;
        s_wnd[wv][jm] = rnd;
    }
    __syncthreads();

    // ---- combine waves; min + hinge in lanes 0-31 of wave 0 ----
    // Sample s: parity g = s&1 lives in waves g*8 .. g*8+7, element j = s>>1.
    if (t < NS) {
        const int sg = t & 1, sj = t >> 1;
        float ap = 0.f, nd = 0.f;
#pragma unroll
        for (int k = 0; k < 8; ++k) {
            ap += s_wap[sg * 8 + k][sj];
            nd += s_wnd[sg * 8 + k][sj];
        }
        float an = nd;
#pragma unroll
        for (int m = 1; m < 32; m <<= 1) an = fminf(an, __shfl_xor(an, m));
        float l = fmaxf(ap - an + MARGIN, 0.f);
#pragma unroll
        for (int m = 1; m < 32; m <<= 1) l += __shfl_xor(l, m);
        if (t == 0) cls[c] = l;
    }
}

// Kernel 2: deterministic mean of the 1024 class losses (proven R2/R6 tail).
__global__ __launch_bounds__(256) void ccl_reduce(const float* __restrict__ class_loss,
                                                  float* __restrict__ out) {
    const int t = threadIdx.x;
    float v = class_loss[t] + class_loss[t + 256] + class_loss[t + 512] + class_loss[t + 768];
#pragma unroll
    for (int m = 32; m >= 1; m >>= 1) v += __shfl_down(v, m);
    __shared__ float s_partial[4];
    if ((t & 63) == 0) s_partial[t >> 6] = v;
    __syncthreads();
    if (t == 0)
        out[0] = (s_partial[0] + s_partial[1] + s_partial[2] + s_partial[3]) * (1.f / NC);
}

extern "C" void kernel_launch(void* const* d_in, const int* in_sizes, int n_in,
                              void* d_out, int out_size, void* d_ws, size_t ws_size,
                              hipStream_t stream) {
    const float* emb = (const float*)d_in[0];   // (2*NC*NS, DD) f32
    float* cls = (float*)d_ws;                  // NC per-class losses
    float* out = (float*)d_out;                 // 1 float
    ccl_per_class<<<NC, 1024, 0, stream>>>(emb, cls);
    ccl_reduce<<<1, 256, 0, stream>>>(cls, out);
}

// Round 10
// 27.151 us; speedup vs baseline: 2.1813x; 1.1781x over previous
//
#include <hip/hip_runtime.h>

#define NC 1024
#define NS 32
#define DD 512
#define MARGIN 0.3f

// Kernel 1: one block per class, 512 threads. Thread t = (g, col4):
// col4 = t&127 is its float4 column, g = t>>7 picks rows s = 4j+g (j<8).
// Per-thread: 8 pos + 8 neg float4 = 64 data VGPRs (same as proven R6), but
// loaded with 16 dwordx4 (1 KB per wave-instruction) instead of 64 dwords --
// 4x fewer VMEM requests, testing the request-rate-limit hypothesis.
// Each wave's 64 lanes cover 1 KB contiguous per load: fully coalesced.
//
// Codegen rules (R3-R8): literal loop bounds only; NO atomics of any
// spelling in this kernel (demotion/serialization); separate reduce kernel.
__global__ __launch_bounds__(512) void ccl_per_class(const float* __restrict__ emb,
                                                     float* __restrict__ cls) {
    const int c = blockIdx.x;
    const int t = threadIdx.x;
    const int g = t >> 7;
    const int col4 = t & 127;
    const int lane = t & 63;
    const int wv = t >> 6;   // = g*2 + colhalf
    const float4* posv = (const float4*)(emb + (size_t)c * (2 * NS * DD));
    const float4* negv = posv + NS * DD / 4;

    __shared__ float4 s_part[4][128];  // per-g column sums (anchor)
    __shared__ float s_wap[8][8];      // per-wave sample partials (ap)
    __shared__ float s_wnd[8][8];      // per-wave sample partials (nd)

    // ---- load 8 pos + 8 neg float4 rows of this column (rows s = 4j+g) ----
    float4 p[8], n[8];
#pragma unroll
    for (int j = 0; j < 8; ++j) p[j] = posv[(4 * j + g) * (DD / 4) + col4];
#pragma unroll
    for (int j = 0; j < 8; ++j) n[j] = negv[(4 * j + g) * (DD / 4) + col4];

    // ---- anchor: per-thread column sum over its 8 rows, LDS combine of 4 g's ----
    float4 acc = p[0];
#pragma unroll
    for (int j = 1; j < 8; ++j) {
        acc.x += p[j].x; acc.y += p[j].y; acc.z += p[j].z; acc.w += p[j].w;
    }
    s_part[g][col4] = acc;
    __syncthreads();
    float4 a;
    {
        float4 x0 = s_part[0][col4], x1 = s_part[1][col4];
        float4 x2 = s_part[2][col4], x3 = s_part[3][col4];
        a.x = (x0.x + x1.x + x2.x + x3.x) * (1.f / NS);
        a.y = (x0.y + x1.y + x2.y + x3.y) * (1.f / NS);
        a.z = (x0.z + x1.z + x2.z + x3.z) * (1.f / NS);
        a.w = (x0.w + x1.w + x2.w + x3.w) * (1.f / NS);
    }

    // ---- per-(sample, column-quad) squared-diff partials ----
    float apc[8], ndc[8];
#pragma unroll
    for (int j = 0; j < 8; ++j) {
        float dx = p[j].x - a.x, dy = p[j].y - a.y, dz = p[j].z - a.z, dw = p[j].w - a.w;
        apc[j] = dx * dx + dy * dy + dz * dz + dw * dw;
        dx = n[j].x - a.x; dy = n[j].y - a.y; dz = n[j].z - a.z; dw = n[j].w - a.w;
        ndc[j] = dx * dx + dy * dy + dz * dz + dw * dw;
    }

    // ---- halving butterfly across the wave's 64 lanes ----
    // Step mask m pairs lanes l, l^m; the (l&m)-set lane keeps the hi half.
#define BSTEP(arr, m, half)                                        \
    {                                                              \
        _Pragma("unroll")                                          \
        for (int i = 0; i < (half); ++i) {                         \
            float lo = arr[i], hi = arr[i + (half)];               \
            float send = (lane & (m)) ? lo : hi;                   \
            float recv = __shfl_xor(send, (m));                    \
            arr[i] = (lane & (m)) ? (hi + recv) : (lo + recv);     \
        }                                                          \
    }
    BSTEP(apc, 1, 4) BSTEP(apc, 2, 2) BSTEP(apc, 4, 1)
    BSTEP(ndc, 1, 4) BSTEP(ndc, 2, 2) BSTEP(ndc, 4, 1)
#undef BSTEP
    // lane holds element j = bitrev3(lane&7) summed over its 8-lane group;
    // fold the eight groups of the wave:
    float rap = apc[0];
    rap += __shfl_xor(rap, 8);
    rap += __shfl_xor(rap, 16);
    rap += __shfl_xor(rap, 32);
    float rnd = ndc[0];
    rnd += __shfl_xor(rnd, 8);
    rnd += __shfl_xor(rnd, 16);
    rnd += __shfl_xor(rnd, 32);
    if (lane < 8) {
        const int jm = ((lane & 1) << 2) | (lane & 2) | ((lane & 4) >> 2);
        s_wap[wv][jm] = rap;
        s_wnd[wv][jm] = rnd;
    }
    __syncthreads();

    // ---- combine column halves; min + hinge in lanes 0-31 of wave 0 ----
    // Sample s = 4*sj + sg lives in waves {sg*2, sg*2+1} at element sj.
    if (t < NS) {
        const int sg = t & 3, sj = t >> 2;
        float ap = s_wap[sg * 2][sj] + s_wap[sg * 2 + 1][sj];
        float nd = s_wnd[sg * 2][sj] + s_wnd[sg * 2 + 1][sj];
        float an = nd;
#pragma unroll
        for (int m = 1; m < 32; m <<= 1) an = fminf(an, __shfl_xor(an, m));
        float l = fmaxf(ap - an + MARGIN, 0.f);
#pragma unroll
        for (int m = 1; m < 32; m <<= 1) l += __shfl_xor(l, m);
        if (t == 0) cls[c] = l;
    }
}

// Kernel 2: deterministic mean of the 1024 class losses (proven R2/R6 tail).
__global__ __launch_bounds__(256) void ccl_reduce(const float* __restrict__ class_loss,
                                                  float* __restrict__ out) {
    const int t = threadIdx.x;
    float v = class_loss[t] + class_loss[t + 256] + class_loss[t + 512] + class_loss[t + 768];
#pragma unroll
    for (int m = 32; m >= 1; m >>= 1) v += __shfl_down(v, m);
    __shared__ float s_partial[4];
    if ((t & 63) == 0) s_partial[t >> 6] = v;
    __syncthreads();
    if (t == 0)
        out[0] = (s_partial[0] + s_partial[1] + s_partial[2] + s_partial[3]) * (1.f / NC);
}

extern "C" void kernel_launch(void* const* d_in, const int* in_sizes, int n_in,
                              void* d_out, int out_size, void* d_ws, size_t ws_size,
                              hipStream_t stream) {
    const float* emb = (const float*)d_in[0];   // (2*NC*NS, DD) f32
    float* cls = (float*)d_ws;                  // NC per-class losses
    float* out = (float*)d_out;                 // 1 float
    ccl_per_class<<<NC, 512, 0, stream>>>(emb, cls);
    ccl_reduce<<<1, 256, 0, stream>>>(cls, out);
}

// Round 11
// 26.605 us; speedup vs baseline: 2.2261x; 1.0205x over previous
//
#include <hip/hip_runtime.h>

#define NC 1024
#define NS 32
#define DD 512
#define MARGIN 0.3f

// Kernel 1: one block per class, 512 threads (8 waves). Wave w owns float4
// columns [w*16, w*16+16); within the wave, lane l = g*16 + c16 owns rows
// s = 4j+g (j<8) of float4 column col4 = w*16 + c16. All 32 rows of each
// column live in ONE wave -> the anchor combine is intra-wave shfl_xor(16,32):
// no barrier, no LDS until the final tail combine. Each wave proceeds as soon
// as its own 16 dwordx4 loads return (no block-wide stall on slowest wave).
//
// Codegen rules (R3-R8): literal loop bounds only (SROA); NO atomics of any
// spelling in this kernel (scratch demotion / coherent-point serialization);
// separate reduce kernel.
__global__ __launch_bounds__(512) void ccl_per_class(const float* __restrict__ emb,
                                                     float* __restrict__ cls) {
    const int c = blockIdx.x;
    const int t = threadIdx.x;
    const int w = t >> 6;
    const int l = t & 63;
    const int g = l >> 4;
    const int c16 = l & 15;
    const int col4 = w * 16 + c16;
    const float4* posv = (const float4*)(emb + (size_t)c * (2 * NS * DD));
    const float4* negv = posv + NS * DD / 4;

    __shared__ float s_wap[8][4][8];  // [wave][g][j] sample partials (ap)
    __shared__ float s_wnd[8][4][8];  // [wave][g][j] sample partials (nd)

    // ---- load 8 pos + 8 neg float4 rows of this column (rows s = 4j+g) ----
    float4 p[8], n[8];
#pragma unroll
    for (int j = 0; j < 8; ++j) p[j] = posv[(4 * j + g) * (DD / 4) + col4];
#pragma unroll
    for (int j = 0; j < 8; ++j) n[j] = negv[(4 * j + g) * (DD / 4) + col4];

    // ---- anchor: 8-row local sum, then fold the 4 g-groups intra-wave ----
    float4 a = p[0];
#pragma unroll
    for (int j = 1; j < 8; ++j) {
        a.x += p[j].x; a.y += p[j].y; a.z += p[j].z; a.w += p[j].w;
    }
    a.x += __shfl_xor(a.x, 16); a.y += __shfl_xor(a.y, 16);
    a.z += __shfl_xor(a.z, 16); a.w += __shfl_xor(a.w, 16);
    a.x += __shfl_xor(a.x, 32); a.y += __shfl_xor(a.y, 32);
    a.z += __shfl_xor(a.z, 32); a.w += __shfl_xor(a.w, 32);
    a.x *= (1.f / NS); a.y *= (1.f / NS); a.z *= (1.f / NS); a.w *= (1.f / NS);

    // ---- per-(sample, column-quad) squared-diff partials ----
    float apc[8], ndc[8];
#pragma unroll
    for (int j = 0; j < 8; ++j) {
        float dx = p[j].x - a.x, dy = p[j].y - a.y, dz = p[j].z - a.z, dw = p[j].w - a.w;
        apc[j] = dx * dx + dy * dy + dz * dz + dw * dw;
        dx = n[j].x - a.x; dy = n[j].y - a.y; dz = n[j].z - a.z; dw = n[j].w - a.w;
        ndc[j] = dx * dx + dy * dy + dz * dz + dw * dw;
    }

    // ---- halving butterfly across the 16 lanes of this g-group ----
    // Step mask m pairs lanes l, l^m; the (l&m)-set lane keeps the hi half.
#define BSTEP(arr, m, half)                                        \
    {                                                              \
        _Pragma("unroll")                                          \
        for (int i = 0; i < (half); ++i) {                         \
            float lo = arr[i], hi = arr[i + (half)];               \
            float send = (l & (m)) ? lo : hi;                      \
            float recv = __shfl_xor(send, (m));                    \
            arr[i] = (l & (m)) ? (hi + recv) : (lo + recv);        \
        }                                                          \
    }
    BSTEP(apc, 1, 4) BSTEP(apc, 2, 2) BSTEP(apc, 4, 1)
    BSTEP(ndc, 1, 4) BSTEP(ndc, 2, 2) BSTEP(ndc, 4, 1)
#undef BSTEP
    // lane holds element j = bitrev3(l&7) summed over its 8-lane subgroup;
    // fold the two subgroups of the 16-lane g-group:
    float rap = apc[0] + __shfl_xor(apc[0], 8);
    float rnd = ndc[0] + __shfl_xor(ndc[0], 8);
    if ((l & 8) == 0) {
        const int jm = ((l & 1) << 2) | (l & 2) | ((l & 4) >> 2);
        s_wap[w][g][jm] = rap;
        s_wnd[w][g][jm] = rnd;
    }
    __syncthreads();

    // ---- combine 8 waves; min + hinge in lanes 0-31 of wave 0 ----
    // Sample s = 4j+g -> g = s&3, j = s>>2.
    if (t < NS) {
        const int sg = t & 3, sj = t >> 2;
        float ap = 0.f, nd = 0.f;
#pragma unroll
        for (int k = 0; k < 8; ++k) {
            ap += s_wap[k][sg][sj];
            nd += s_wnd[k][sg][sj];
        }
        float an = nd;
#pragma unroll
        for (int m = 1; m < 32; m <<= 1) an = fminf(an, __shfl_xor(an, m));
        float hl = fmaxf(ap - an + MARGIN, 0.f);
#pragma unroll
        for (int m = 1; m < 32; m <<= 1) hl += __shfl_xor(hl, m);
        if (t == 0) cls[c] = hl;
    }
}

// Kernel 2: single-wave deterministic mean of the 1024 class losses.
// 64 threads, 4 float4 loads each, pure shuffle reduce -- no LDS, no barrier.
__global__ __launch_bounds__(64) void ccl_reduce(const float* __restrict__ class_loss,
                                                 float* __restrict__ out) {
    const int t = threadIdx.x;
    const float4* v4 = (const float4*)class_loss;  // 256 float4
    float4 x0 = v4[t], x1 = v4[t + 64], x2 = v4[t + 128], x3 = v4[t + 192];
    float v = (x0.x + x0.y + x0.z + x0.w) + (x1.x + x1.y + x1.z + x1.w) +
              (x2.x + x2.y + x2.z + x2.w) + (x3.x + x3.y + x3.z + x3.w);
#pragma unroll
    for (int m = 1; m < 64; m <<= 1) v += __shfl_xor(v, m);
    if (t == 0) out[0] = v * (1.f / NC);
}

extern "C" void kernel_launch(void* const* d_in, const int* in_sizes, int n_in,
                              void* d_out, int out_size, void* d_ws, size_t ws_size,
                              hipStream_t stream) {
    const float* emb = (const float*)d_in[0];   // (2*NC*NS, DD) f32
    float* cls = (float*)d_ws;                  // NC per-class losses
    float* out = (float*)d_out;                 // 1 float
    ccl_per_class<<<NC, 512, 0, stream>>>(emb, cls);
    ccl_reduce<<<1, 64, 0, stream>>>(cls, out);
}